// Round 3
// baseline (548.708 us; speedup 1.0000x reference)
//
#include <hip/hip_runtime.h>
#include <hip/hip_bf16.h>

// GRU teacher-forced NLL, B=8192, S=2048, H=8, IN_DIM=4, NCLS=10.
// 16 lanes per batch element (131072 threads = 2 waves/SIMD machine-wide).
// Within a 16-lane group: half A (lanes 0-7) owns r-gate & n-gate for comp i;
// half B (lanes 8-15) owns z-gate & logit classes 8/9. One exp2/rcp instruction
// serves both halves (paired in lanes). Halves exchange z<->n via ROW_ROR:8
// DPP (xor8 within 16). h replicated per-lane via 7-DPP butterfly (quad_perm
// xor1/xor2 + ROW_HALF_MIRROR xor7) serving both halves at once; weight rows
// pre-permuted to gather order perm=[0,1,2,3,7,6,5,4].
// All pre-activations prescaled by log2(e) (2*log2(e) for tanh); log-softmax in
// base 2; log2 amortized by accumulating 8-step products of the softmax sum s
// (s in [0.5,200] -> product in fp32 range). Input-side matmuls: 10-entry LDS
// float2 table (A: (r-init, n-init), B: (z-init, 0)), prefetched one step
// ahead (next input == current target).

#define SEQ   2048
#define BATCH 8192

typedef float f2 __attribute__((ext_vector_type(2)));

static __device__ __forceinline__ float xor1f(float x) {
    int r = __builtin_amdgcn_update_dpp(__builtin_bit_cast(int, x),
                                        __builtin_bit_cast(int, x),
                                        0xB1 /*quad_perm [1,0,3,2]*/, 0xF, 0xF, true);
    return __builtin_bit_cast(float, r);
}
static __device__ __forceinline__ float xor2f(float x) {
    int r = __builtin_amdgcn_update_dpp(__builtin_bit_cast(int, x),
                                        __builtin_bit_cast(int, x),
                                        0x4E /*quad_perm [2,3,0,1]*/, 0xF, 0xF, true);
    return __builtin_bit_cast(float, r);
}
static __device__ __forceinline__ float hmf(float x) {
    // ROW_HALF_MIRROR: lane -> lane ^ 7 within each 8-lane half-row
    int r = __builtin_amdgcn_update_dpp(__builtin_bit_cast(int, x),
                                        __builtin_bit_cast(int, x),
                                        0x141, 0xF, 0xF, true);
    return __builtin_bit_cast(float, r);
}
static __device__ __forceinline__ float ror8f(float x) {
    // ROW_ROR:8 : within each 16-lane row, lane n <- lane (n+8)%16 == lane n^8
    int r = __builtin_amdgcn_update_dpp(__builtin_bit_cast(int, x),
                                        __builtin_bit_cast(int, x),
                                        0x128, 0xF, 0xF, true);
    return __builtin_bit_cast(float, r);
}

__global__ __launch_bounds__(256, 2)
void gru_nll_kernel(const int* __restrict__ xb,
                    const float* __restrict__ Wir, const float* __restrict__ bir,
                    const float* __restrict__ Wiz, const float* __restrict__ biz,
                    const float* __restrict__ Win, const float* __restrict__ bin_,
                    const float* __restrict__ Whr, const float* __restrict__ bhr,
                    const float* __restrict__ Whz, const float* __restrict__ bhz,
                    const float* __restrict__ Whn, const float* __restrict__ bhn,
                    const float* __restrict__ Wout, const float* __restrict__ bout,
                    float* __restrict__ out)
{
    constexpr float S1 = 1.4426950408889634f;   // log2(e)
    __shared__ float2 t16[10][16];
    __shared__ float red[256];

    const int tid = threadIdx.x;

    // ---- build input-contribution table ----
    if (tid < 160) {
        int c = tid >> 4, p = tid & 15, ii = p & 7;
        float b0 = (float)((c >> 3) & 1);
        float b1 = (float)((c >> 2) & 1);
        float b2 = (float)((c >> 1) & 1);
        float b3 = (float)(c & 1);
        float2 v;
        if (p < 8) {
            float gr = bir[ii] + bhr[ii]
                     + b0*Wir[ii*4+0] + b1*Wir[ii*4+1] + b2*Wir[ii*4+2] + b3*Wir[ii*4+3];
            float gn = bin_[ii]
                     + b0*Win[ii*4+0] + b1*Win[ii*4+1] + b2*Win[ii*4+2] + b3*Win[ii*4+3];
            v.x = S1 * gr;
            v.y = 2.0f * S1 * gn;
        } else {
            float gz = biz[ii] + bhz[ii]
                     + b0*Wiz[ii*4+0] + b1*Wiz[ii*4+1] + b2*Wiz[ii*4+2] + b3*Wiz[ii*4+3];
            v.x = S1 * gz;
            v.y = 0.0f;
        }
        t16[c][p] = v;
    }

    const int lane   = tid & 63;
    const int i      = lane & 7;          // hidden component owned
    const int p      = lane & 15;         // position within 16-lane group
    const bool ahalf = (lane & 8) != 0;   // false = A (r/n), true = B (z/logitB)
    const int b      = blockIdx.x * 16 + (tid >> 4);   // batch element

    const int perm[8] = {0, 1, 2, 3, 7, 6, 5, 4};

    // dot1: A: S1*Whr row i | B: S1*Whz row i
    // dot2: A: 2*S1*Whn row i | B: zeros
    // dot3: A: S1*Wout row i | B: i<2 ? S1*Wout row 8+i : zeros
    f2 w1P[4], w2P[4], w3P[4];
    #pragma unroll
    for (int q = 0; q < 4; ++q) {
        int c0 = i ^ perm[2*q], c1 = i ^ perm[2*q+1];
        if (!ahalf) {
            w1P[q] = f2{S1 * Whr[i*8 + c0],      S1 * Whr[i*8 + c1]};
            w2P[q] = f2{2.0f*S1 * Whn[i*8 + c0], 2.0f*S1 * Whn[i*8 + c1]};
            w3P[q] = f2{S1 * Wout[i*8 + c0],     S1 * Wout[i*8 + c1]};
        } else {
            w1P[q] = f2{S1 * Whz[i*8 + c0],      S1 * Whz[i*8 + c1]};
            w2P[q] = f2{0.0f, 0.0f};
            w3P[q] = (i < 2) ? f2{S1 * Wout[(8+i)*8 + c0], S1 * Wout[(8+i)*8 + c1]}
                             : f2{0.0f, 0.0f};
        }
    }
    const float hn0 = ahalf ? 0.0f : 2.0f * S1 * bhn[i];
    const float lg0 = ahalf ? ((i < 2) ? S1 * bout[8+i] : -1e30f)   // exp2 -> 0
                            : S1 * bout[i];
    const int myclass = (ahalf ? 8 : 0) + i;

    __syncthreads();

    const int4* row4 = (const int4*)(xb + (size_t)b * SEQ);

    f2 H[4];
    #pragma unroll
    for (int q = 0; q < 4; ++q) H[q] = f2{0.0f, 0.0f};

    float accp = 0.0f;   // sum of log2(prod s), duplicated x16 per element
    float acct = 0.0f;   // sum of target logits (base-2 units), x1 per element
    float P    = 1.0f;

    float2 g = t16[0][p];   // first input count = 0

    auto step = [&](int t) {
        float2 gnx = t16[t][p];   // prefetch next step's entry

        f2 a1P = f2{g.x, 0.0f}, a2P = f2{hn0, 0.0f};
        #pragma unroll
        for (int q = 0; q < 4; ++q) {
            a1P += w1P[q] * H[q];
            a2P += w2P[q] * H[q];
        }
        float a1 = a1P.x + a1P.y;       // A: ar | B: az   (log2e-scaled)
        float hn = a2P.x + a2P.y;       // A: hn | B: 0

        // paired sigmoid: R = A: r | B: z
        float R = __builtin_amdgcn_rcpf(1.0f + __builtin_amdgcn_exp2f(-a1));
        float Z = ror8f(R);             // A gets z, B gets r
        float u = __builtin_fmaf(R, hn, g.y);   // A: 2log2e * v | B: 0
        float N = __builtin_fmaf(-2.0f,
                    __builtin_amdgcn_rcpf(1.0f + __builtin_amdgcn_exp2f(u)), 1.0f);
        float Nx = ror8f(N);            // B gets n
        float zv = ahalf ? R : Z;       // z in both halves
        float nv = ahalf ? Nx : N;      // n in both halves
        float h0 = H[0].x;              // own previous h_i
        float hnew = __builtin_fmaf(zv, h0 - nv, nv);

        // butterfly all-gather (serves both halves): reg m <- h[i ^ perm[m]]
        float v0 = hnew;
        float v1 = xor1f(v0);
        float v2 = xor2f(v0);
        float v3 = xor2f(v1);
        float v4 = hmf(v0);
        float v5 = hmf(v1);
        float v6 = hmf(v2);
        float v7 = hmf(v3);
        H[0] = f2{v0, v1}; H[1] = f2{v2, v3}; H[2] = f2{v4, v5}; H[3] = f2{v6, v7};

        // logits: A lane i -> class i | B lane i -> class 8+i (i<2)
        f2 a3P = f2{lg0, 0.0f};
        #pragma unroll
        for (int q = 0; q < 4; ++q) a3P += w3P[q] * H[q];
        float l = a3P.x + a3P.y;

        float s = __builtin_amdgcn_exp2f(l);
        s += xor1f(s);
        s += xor2f(s);
        s += hmf(s);        // quad sums are quad-uniform: xor7 == xor4 here
        s += ror8f(s);      // combine the two 8-halves: full 10-class sum
        P *= s;

        if (myclass == t) acct += l;    // one lane per element owns the target

        g = gnx;
    };

    for (int jb = 0; jb < SEQ/8; ++jb) {
        int base = 2*jb;
        int4 cA = row4[base];
        int4 cB = row4[base + 1];
        step(cA.x); step(cA.y); step(cA.z); step(cA.w);
        step(cB.x); step(cB.y); step(cB.z); step(cB.w);
        accp += __builtin_amdgcn_logf(P);   // log2
        P = 1.0f;
    }

    // contribution = ln2 * (sum log2 s - l_t); accp duplicated x16 -> /16
    red[tid] = __builtin_fmaf(accp, 0.0625f, -acct);
    __syncthreads();
    #pragma unroll
    for (int sft = 128; sft > 0; sft >>= 1) {
        if (tid < sft) red[tid] += red[tid + sft];
        __syncthreads();
    }
    if (tid == 0) {
        constexpr float SCALE =
            (float)(0.69314718055994530942 / (8192.0 * 2048.0));
        atomicAdd(out, red[0] * SCALE);
    }
}

extern "C" void kernel_launch(void* const* d_in, const int* in_sizes, int n_in,
                              void* d_out, int out_size, void* d_ws, size_t ws_size,
                              hipStream_t stream) {
    hipMemsetAsync(d_out, 0, sizeof(float), stream);
    gru_nll_kernel<<<BATCH * 16 / 256, 256, 0, stream>>>(
        (const int*)d_in[0],
        (const float*)d_in[1],  (const float*)d_in[2],
        (const float*)d_in[3],  (const float*)d_in[4],
        (const float*)d_in[5],  (const float*)d_in[6],
        (const float*)d_in[7],  (const float*)d_in[8],
        (const float*)d_in[9],  (const float*)d_in[10],
        (const float*)d_in[11], (const float*)d_in[12],
        (const float*)d_in[13], (const float*)d_in[14],
        (float*)d_out);
}

// Round 4
// 478.780 us; speedup vs baseline: 1.1461x; 1.1461x over previous
//
#include <hip/hip_runtime.h>
#include <hip/hip_bf16.h>

// GRU teacher-forced NLL, B=8192, S=2048, H=8, IN_DIM=4, NCLS=10.
// PRODUCER-CONSUMER wave specialization, 2 waves/SIMD, no duplicated work:
//   recur waves: 8 lanes/element, gates + hnew + DPP butterfly, write h to an
//     LDS ring buffer (double-buffered, KS=8 steps per phase, barrier/phase).
//   softmax waves: read h (natural order, 2x ds_read_b128, no butterfly),
//     logits + softmax-sum + NLL with the 8-step product trick for log2.
// Roles are XORed with blockIdx>>8 so the two blocks co-resident on a CU mix
// recur/softmax waves across SIMDs. All pre-activations prescaled by log2(e)
// (2*log2(e) for tanh); nonlinearities are raw v_exp_f32/v_rcp_f32; one ln2
// scale at the end. Input-side matmuls: 10-entry LDS float4 table (prefetched
// one step ahead; next input == current target).

#define SEQ   2048
#define BATCH 8192
#define KS    8
#define NPH   (SEQ / KS)

typedef float f2 __attribute__((ext_vector_type(2)));

static __device__ __forceinline__ float xor1f(float x) {
    int r = __builtin_amdgcn_update_dpp(__builtin_bit_cast(int, x),
                                        __builtin_bit_cast(int, x),
                                        0xB1 /*quad_perm [1,0,3,2]*/, 0xF, 0xF, true);
    return __builtin_bit_cast(float, r);
}
static __device__ __forceinline__ float xor2f(float x) {
    int r = __builtin_amdgcn_update_dpp(__builtin_bit_cast(int, x),
                                        __builtin_bit_cast(int, x),
                                        0x4E /*quad_perm [2,3,0,1]*/, 0xF, 0xF, true);
    return __builtin_bit_cast(float, r);
}
static __device__ __forceinline__ float hmf(float x) {
    // ROW_HALF_MIRROR: lane -> lane ^ 7 within each 8-lane half-row
    int r = __builtin_amdgcn_update_dpp(__builtin_bit_cast(int, x),
                                        __builtin_bit_cast(int, x),
                                        0x141, 0xF, 0xF, true);
    return __builtin_bit_cast(float, r);
}

__global__ __launch_bounds__(256, 2)
void gru_nll_kernel(const int* __restrict__ xb,
                    const float* __restrict__ Wir, const float* __restrict__ bir,
                    const float* __restrict__ Wiz, const float* __restrict__ biz,
                    const float* __restrict__ Win, const float* __restrict__ bin_,
                    const float* __restrict__ Whr, const float* __restrict__ bhr,
                    const float* __restrict__ Whz, const float* __restrict__ bhz,
                    const float* __restrict__ Whn, const float* __restrict__ bhn,
                    const float* __restrict__ Wout, const float* __restrict__ bout,
                    float* __restrict__ out)
{
    constexpr float S1 = 1.4426950408889634f;   // log2(e)
    __shared__ float4 tbl[10][8];               // [count][i] = {gr', gz', gn', 0}
    __shared__ float  hbuf[2][KS][16][8];       // 8 KB double-buffered h ring
    __shared__ float  red[256];

    const int tid = threadIdx.x;

    if (tid < 80) {
        int c = tid >> 3, ii = tid & 7;
        float b0 = (float)((c >> 3) & 1);
        float b1 = (float)((c >> 2) & 1);
        float b2 = (float)((c >> 1) & 1);
        float b3 = (float)(c & 1);
        float gr = bir[ii] + bhr[ii]
                 + b0*Wir[ii*4+0] + b1*Wir[ii*4+1] + b2*Wir[ii*4+2] + b3*Wir[ii*4+3];
        float gz = biz[ii] + bhz[ii]
                 + b0*Wiz[ii*4+0] + b1*Wiz[ii*4+1] + b2*Wiz[ii*4+2] + b3*Wiz[ii*4+3];
        float gn = bin_[ii]
                 + b0*Win[ii*4+0] + b1*Win[ii*4+1] + b2*Win[ii*4+2] + b3*Win[ii*4+3];
        tbl[c][ii] = make_float4(S1 * gr, S1 * gz, 2.0f * S1 * gn, 0.0f);
    }
    __syncthreads();

    const int lane  = tid & 63;
    const int i     = lane & 7;                 // hidden comp / class owned
    const int w     = tid >> 6;
    const int grp   = w & 1;                    // element half within block
    const int role  = ((w >> 1) ^ (blockIdx.x >> 8)) & 1;  // 0=recur, 1=softmax
    const int e_loc = grp * 8 + (lane >> 3);    // 0..15 within block
    const int b     = blockIdx.x * 16 + e_loc;  // batch element
    const int4* row4 = (const int4*)(xb + (size_t)b * SEQ);

    float myred;

    if (role == 0) {
        // ---------------- recurrence producer ----------------
        const int perm[8] = {0, 1, 2, 3, 7, 6, 5, 4};
        f2 whr[4], whz[4], whn[4];
        #pragma unroll
        for (int q = 0; q < 4; ++q) {
            int c0 = i ^ perm[2*q], c1 = i ^ perm[2*q+1];
            whr[q] = f2{S1 * Whr[i*8 + c0],      S1 * Whr[i*8 + c1]};
            whz[q] = f2{S1 * Whz[i*8 + c0],      S1 * Whz[i*8 + c1]};
            whn[q] = f2{2.0f*S1 * Whn[i*8 + c0], 2.0f*S1 * Whn[i*8 + c1]};
        }
        const float ghn_b = 2.0f * S1 * bhn[i];

        f2 H[4];
        #pragma unroll
        for (int q = 0; q < 4; ++q) H[q] = f2{0.0f, 0.0f};
        float4 g = tbl[0][i];                   // first input count = 0
        int4 cA = row4[0], cB = row4[1];        // targets of phase 0

        for (int ph = 0; ph < NPH + 1; ++ph) {
            if (ph < NPH) {
                int4 nA = cA, nB = cB;
                if (ph + 1 < NPH) { nA = row4[2*ph + 2]; nB = row4[2*ph + 3]; }
                float* hb = &hbuf[ph & 1][0][e_loc][i];
                const int ts[8] = {cA.x, cA.y, cA.z, cA.w, cB.x, cB.y, cB.z, cB.w};
                #pragma unroll
                for (int st = 0; st < 8; ++st) {
                    int t = ts[st];
                    float4 gnx = tbl[t][i];     // next input's table entry
                    f2 a1P = f2{g.x, 0.0f}, a2P = f2{g.y, 0.0f}, a3P = f2{ghn_b, 0.0f};
                    #pragma unroll
                    for (int q = 0; q < 4; ++q) {
                        a1P += whr[q] * H[q];
                        a2P += whz[q] * H[q];
                        a3P += whn[q] * H[q];
                    }
                    float ar = a1P.x + a1P.y;
                    float az = a2P.x + a2P.y;
                    float hn = a3P.x + a3P.y;
                    float r = __builtin_amdgcn_rcpf(1.0f + __builtin_amdgcn_exp2f(-ar));
                    float z = __builtin_amdgcn_rcpf(1.0f + __builtin_amdgcn_exp2f(-az));
                    float u = __builtin_fmaf(r, hn, g.z);
                    float n = __builtin_fmaf(-2.0f,
                                __builtin_amdgcn_rcpf(1.0f + __builtin_amdgcn_exp2f(u)),
                                1.0f);
                    float h0 = H[0].x;
                    float hnew = __builtin_fmaf(z, h0 - n, n);
                    hb[st * 128] = hnew;        // stride = 16 elem * 8 comp
                    float v0 = hnew;
                    float v1 = xor1f(v0);
                    float v2 = xor2f(v0);
                    float v3 = xor2f(v1);
                    float v4 = hmf(v0);
                    float v5 = hmf(v1);
                    float v6 = hmf(v2);
                    float v7 = hmf(v3);
                    H[0] = f2{v0, v1}; H[1] = f2{v2, v3};
                    H[2] = f2{v4, v5}; H[3] = f2{v6, v7};
                    g = gnx;
                }
                cA = nA; cB = nB;
            }
            __syncthreads();
        }
        myred = 0.0f;
    } else {
        // ---------------- softmax / NLL consumer ----------------
        f2 wA[4], wB[4];                        // NATURAL column order
        #pragma unroll
        for (int q = 0; q < 4; ++q) {
            wA[q] = f2{S1 * Wout[i*8 + 2*q], S1 * Wout[i*8 + 2*q + 1]};
            wB[q] = (i < 2) ? f2{S1 * Wout[(8+i)*8 + 2*q], S1 * Wout[(8+i)*8 + 2*q + 1]}
                            : f2{0.0f, 0.0f};
        }
        const float lg0A = S1 * bout[i];
        const float lg0B = (i < 2) ? S1 * bout[8+i] : -1e30f;   // exp2 -> 0

        float accp = 0.0f;                      // x8 duplicated per element
        float acct = 0.0f;                      // x1 per element
        int4 cA = row4[0], cB = row4[1];        // targets of phase 0

        for (int ph = 0; ph < NPH + 1; ++ph) {
            if (ph > 0) {
                int q_ph = ph - 1;
                int4 nA = cA, nB = cB;
                if (ph < NPH) { nA = row4[2*ph]; nB = row4[2*ph + 1]; }
                const float* hb = &hbuf[q_ph & 1][0][e_loc][0];
                const int ts[8] = {cA.x, cA.y, cA.z, cA.w, cB.x, cB.y, cB.z, cB.w};
                float P = 1.0f;
                #pragma unroll
                for (int st = 0; st < 8; ++st) {
                    float4 h03 = *(const float4*)(hb + st * 128);
                    float4 h47 = *(const float4*)(hb + st * 128 + 4);
                    f2 H0 = f2{h03.x, h03.y}, H1 = f2{h03.z, h03.w};
                    f2 H2 = f2{h47.x, h47.y}, H3 = f2{h47.z, h47.w};
                    f2 lAP = f2{lg0A, 0.0f}, lBP = f2{lg0B, 0.0f};
                    lAP += wA[0]*H0; lBP += wB[0]*H0;
                    lAP += wA[1]*H1; lBP += wB[1]*H1;
                    lAP += wA[2]*H2; lBP += wB[2]*H2;
                    lAP += wA[3]*H3; lBP += wB[3]*H3;
                    float lA = lAP.x + lAP.y;
                    float lB = lBP.x + lBP.y;
                    float s = __builtin_amdgcn_exp2f(lA) + __builtin_amdgcn_exp2f(lB);
                    s += xor1f(s);
                    s += xor2f(s);
                    s += hmf(s);    // quad sums are quad-uniform: xor7 == xor4
                    P *= s;
                    int t = ts[st];
                    float sel = (t >= 8) ? lB : lA;
                    if ((t & 7) == i) acct += sel;
                }
                accp += __builtin_amdgcn_logf(P);   // log2
                cA = nA; cB = nB;
            }
            __syncthreads();
        }
        myred = __builtin_fmaf(accp, 0.125f, -acct);
    }

    red[tid] = myred;
    __syncthreads();
    #pragma unroll
    for (int sft = 128; sft > 0; sft >>= 1) {
        if (tid < sft) red[tid] += red[tid + sft];
        __syncthreads();
    }
    if (tid == 0) {
        constexpr float SCALE =
            (float)(0.69314718055994530942 / (8192.0 * 2048.0));
        atomicAdd(out, red[0] * SCALE);
    }
}

extern "C" void kernel_launch(void* const* d_in, const int* in_sizes, int n_in,
                              void* d_out, int out_size, void* d_ws, size_t ws_size,
                              hipStream_t stream) {
    hipMemsetAsync(d_out, 0, sizeof(float), stream);
    gru_nll_kernel<<<BATCH * 16 / 256, 256, 0, stream>>>(
        (const int*)d_in[0],
        (const float*)d_in[1],  (const float*)d_in[2],
        (const float*)d_in[3],  (const float*)d_in[4],
        (const float*)d_in[5],  (const float*)d_in[6],
        (const float*)d_in[7],  (const float*)d_in[8],
        (const float*)d_in[9],  (const float*)d_in[10],
        (const float*)d_in[11], (const float*)d_in[12],
        (const float*)d_in[13], (const float*)d_in[14],
        (float*)d_out);
}

// Round 5
// 415.662 us; speedup vs baseline: 1.3201x; 1.1519x over previous
//
#include <hip/hip_runtime.h>
#include <hip/hip_bf16.h>

// GRU teacher-forced NLL, B=8192, S=2048, H=8, IN_DIM=4, NCLS=10.
// R2 skeleton (8 lanes/element, 1 wave/SIMD, all-DPP butterfly, prescaled
// exp2-domain gates, 8-step softmax product trick) plus:
//  - f16 v_dot2_f32_f16 dots (full-rate, fp32 accumulate; init = LDS table
//    entry so horizontal adds vanish). Own-component h stays exact fp32;
//    only cross-lane dot inputs round to f16 (~5e-4 rel).
//  - explicit softmax lag: step t's body consumes step t-1's softmax between
//    the gate-dot issue and the sigmoid/tanh chain -> guaranteed independent
//    work inside the trans latency. First pending is a dummy (s-sum = 8
//    exactly), corrected by accp -= 3 at the end.

#define SEQ   2048
#define BATCH 8192

using hh2 = decltype(__builtin_amdgcn_cvt_pkrtz(0.0f, 0.0f));

static __device__ __forceinline__ float xor1f(float x) {
    int r = __builtin_amdgcn_update_dpp(__builtin_bit_cast(int, x),
                                        __builtin_bit_cast(int, x),
                                        0xB1 /*quad_perm [1,0,3,2]*/, 0xF, 0xF, true);
    return __builtin_bit_cast(float, r);
}
static __device__ __forceinline__ float xor2f(float x) {
    int r = __builtin_amdgcn_update_dpp(__builtin_bit_cast(int, x),
                                        __builtin_bit_cast(int, x),
                                        0x4E /*quad_perm [2,3,0,1]*/, 0xF, 0xF, true);
    return __builtin_bit_cast(float, r);
}
static __device__ __forceinline__ float hmf(float x) {
    // ROW_HALF_MIRROR: lane -> lane ^ 7 within each 8-lane half-row
    int r = __builtin_amdgcn_update_dpp(__builtin_bit_cast(int, x),
                                        __builtin_bit_cast(int, x),
                                        0x141, 0xF, 0xF, true);
    return __builtin_bit_cast(float, r);
}

static __device__ __forceinline__ float dot2(hh2 a, hh2 b, float c) {
#if __has_builtin(__builtin_amdgcn_fdot2)
    return __builtin_amdgcn_fdot2(a, b, c, false);
#else
    return c + (float)a[0] * (float)b[0] + (float)a[1] * (float)b[1];
#endif
}

__global__ __launch_bounds__(256, 1)
void gru_nll_kernel(const int* __restrict__ xb,
                    const float* __restrict__ Wir, const float* __restrict__ bir,
                    const float* __restrict__ Wiz, const float* __restrict__ biz,
                    const float* __restrict__ Win, const float* __restrict__ bin_,
                    const float* __restrict__ Whr, const float* __restrict__ bhr,
                    const float* __restrict__ Whz, const float* __restrict__ bhz,
                    const float* __restrict__ Whn, const float* __restrict__ bhn,
                    const float* __restrict__ Wout, const float* __restrict__ bout,
                    float* __restrict__ out)
{
    constexpr float S1 = 1.4426950408889634f;   // log2(e)
    __shared__ float4 tbl[10][8];               // [count][i] = {gr', gz', gn', 0}
    __shared__ float  red[256];

    const int tid = threadIdx.x;

    if (tid < 80) {
        int c = tid >> 3, ii = tid & 7;
        float b0 = (float)((c >> 3) & 1);
        float b1 = (float)((c >> 2) & 1);
        float b2 = (float)((c >> 1) & 1);
        float b3 = (float)(c & 1);
        float gr = bir[ii] + bhr[ii]
                 + b0*Wir[ii*4+0] + b1*Wir[ii*4+1] + b2*Wir[ii*4+2] + b3*Wir[ii*4+3];
        float gz = biz[ii] + bhz[ii]
                 + b0*Wiz[ii*4+0] + b1*Wiz[ii*4+1] + b2*Wiz[ii*4+2] + b3*Wiz[ii*4+3];
        float gn = bin_[ii]
                 + b0*Win[ii*4+0] + b1*Win[ii*4+1] + b2*Win[ii*4+2] + b3*Win[ii*4+3];
        tbl[c][ii] = make_float4(S1 * gr, S1 * gz, 2.0f * S1 * gn, 0.0f);
    }
    __syncthreads();

    const int lane = tid & 63;
    const int i    = lane & 7;                    // hidden comp / class owned
    const int b    = blockIdx.x * 32 + (tid >> 3);

    const int perm[8] = {0, 1, 2, 3, 7, 6, 5, 4};

    // f16 weight pairs in butterfly gather order: reg q holds cols
    // (i^perm[2q], i^perm[2q+1]); scales folded in (S1, 2*S1 for tanh gate).
    hh2 whr[4], whz[4], whn[4], wA[4], wB[4];
    #pragma unroll
    for (int q = 0; q < 4; ++q) {
        int c0 = i ^ perm[2*q], c1 = i ^ perm[2*q+1];
        whr[q] = __builtin_amdgcn_cvt_pkrtz(S1 * Whr[i*8 + c0],      S1 * Whr[i*8 + c1]);
        whz[q] = __builtin_amdgcn_cvt_pkrtz(S1 * Whz[i*8 + c0],      S1 * Whz[i*8 + c1]);
        whn[q] = __builtin_amdgcn_cvt_pkrtz(2.0f*S1 * Whn[i*8 + c0], 2.0f*S1 * Whn[i*8 + c1]);
        wA[q]  = __builtin_amdgcn_cvt_pkrtz(S1 * Wout[i*8 + c0],     S1 * Wout[i*8 + c1]);
        wB[q]  = (i < 2)
               ? __builtin_amdgcn_cvt_pkrtz(S1 * Wout[(8+i)*8 + c0], S1 * Wout[(8+i)*8 + c1])
               : __builtin_amdgcn_cvt_pkrtz(0.0f, 0.0f);
    }
    const float ghn_b = 2.0f * S1 * bhn[i];
    const float bA    = S1 * bout[i];
    const float bB    = (i < 2) ? S1 * bout[8+i] : -1e30f;   // exp2 -> 0

    const int4* row4 = (const int4*)(xb + (size_t)b * SEQ);

    hh2 Hh[4];
    #pragma unroll
    for (int q = 0; q < 4; ++q) Hh[q] = __builtin_amdgcn_cvt_pkrtz(0.0f, 0.0f);
    float hprev = 0.0f;                     // own h_i, exact fp32

    float accp = 0.0f;                      // x8 duplicated per element (log2)
    float acct = 0.0f;                      // x1 per element (base-2 logits)
    float P    = 1.0f;

    // pending softmax (lagged by one step); dummy: s-sum = 8 exactly
    float pLA = 0.0f, pLB = -1e30f;
    int   pT  = 0;

    float4 g = tbl[0][i];                   // first input count = 0

    auto stepf = [&](int t) {
        float4 gnx = *(const float4*)&tbl[t][i];   // next input's table entry

        float ar = g.x, az = g.y, hn = ghn_b;
        #pragma unroll
        for (int q = 0; q < 4; ++q) {
            ar = dot2(Hh[q], whr[q], ar);
            az = dot2(Hh[q], whz[q], az);
            hn = dot2(Hh[q], whn[q], hn);
        }

        // ---- consume previous step's softmax (independent of gate chain) ----
        {
            float s = __builtin_amdgcn_exp2f(pLA) + __builtin_amdgcn_exp2f(pLB);
            s += xor1f(s);
            s += xor2f(s);
            s += hmf(s);        // quad sums are quad-uniform: xor7 == xor4
            P *= s;
            float sel = (pT >= 8) ? pLB : pLA;
            if ((pT & 7) == i) acct += sel;
        }

        float r = __builtin_amdgcn_rcpf(1.0f + __builtin_amdgcn_exp2f(-ar));
        float z = __builtin_amdgcn_rcpf(1.0f + __builtin_amdgcn_exp2f(-az));
        float u = __builtin_fmaf(r, hn, g.z);
        float n = __builtin_fmaf(-2.0f,
                    __builtin_amdgcn_rcpf(1.0f + __builtin_amdgcn_exp2f(u)), 1.0f);
        float hnew = __builtin_fmaf(z, hprev - n, n);
        hprev = hnew;

        // all-DPP butterfly: reg m <- h[i ^ perm[m]] (fp32), then pack to f16
        float v0 = hnew;
        float v1 = xor1f(v0);
        float v2 = xor2f(v0);
        float v3 = xor2f(v1);
        float v4 = hmf(v0);
        float v5 = hmf(v1);
        float v6 = hmf(v2);
        float v7 = hmf(v3);
        Hh[0] = __builtin_amdgcn_cvt_pkrtz(v0, v1);
        Hh[1] = __builtin_amdgcn_cvt_pkrtz(v2, v3);
        Hh[2] = __builtin_amdgcn_cvt_pkrtz(v4, v5);
        Hh[3] = __builtin_amdgcn_cvt_pkrtz(v6, v7);

        float lA = bA, lB = bB;
        #pragma unroll
        for (int q = 0; q < 4; ++q) {
            lA = dot2(Hh[q], wA[q], lA);
            lB = dot2(Hh[q], wB[q], lB);
        }
        pLA = lA; pLB = lB; pT = t;
        g = gnx;
    };

    int4 cc = row4[0];
    int4 cd = row4[1];
    for (int jb = 0; jb < SEQ/8; ++jb) {
        int4 nA = cc, nB = cd;
        if (jb + 1 < SEQ/8) { nA = row4[2*jb + 2]; nB = row4[2*jb + 3]; }
        stepf(cc.x); stepf(cc.y); stepf(cc.z); stepf(cc.w);
        stepf(cd.x); stepf(cd.y); stepf(cd.z); stepf(cd.w);
        accp += __builtin_amdgcn_logf(P);   // log2
        P = 1.0f;
        cc = nA; cd = nB;
    }

    // final pending consume (step SEQ-1)
    {
        float s = __builtin_amdgcn_exp2f(pLA) + __builtin_amdgcn_exp2f(pLB);
        s += xor1f(s);
        s += xor2f(s);
        s += hmf(s);
        accp += __builtin_amdgcn_logf(s);
        float sel = (pT >= 8) ? pLB : pLA;
        if ((pT & 7) == i) acct += sel;
    }
    accp -= 3.0f;                           // remove dummy's log2(8)

    red[tid] = __builtin_fmaf(accp, 0.125f, -acct);
    __syncthreads();
    #pragma unroll
    for (int sft = 128; sft > 0; sft >>= 1) {
        if (tid < sft) red[tid] += red[tid + sft];
        __syncthreads();
    }
    if (tid == 0) {
        constexpr float SCALE =
            (float)(0.69314718055994530942 / (8192.0 * 2048.0));
        atomicAdd(out, red[0] * SCALE);
    }
}

extern "C" void kernel_launch(void* const* d_in, const int* in_sizes, int n_in,
                              void* d_out, int out_size, void* d_ws, size_t ws_size,
                              hipStream_t stream) {
    hipMemsetAsync(d_out, 0, sizeof(float), stream);
    gru_nll_kernel<<<BATCH * 8 / 256, 256, 0, stream>>>(
        (const int*)d_in[0],
        (const float*)d_in[1],  (const float*)d_in[2],
        (const float*)d_in[3],  (const float*)d_in[4],
        (const float*)d_in[5],  (const float*)d_in[6],
        (const float*)d_in[7],  (const float*)d_in[8],
        (const float*)d_in[9],  (const float*)d_in[10],
        (const float*)d_in[11], (const float*)d_in[12],
        (const float*)d_in[13], (const float*)d_in[14],
        (float*)d_out);
}

// Round 7
// 383.927 us; speedup vs baseline: 1.4292x; 1.0827x over previous
//
#include <hip/hip_runtime.h>
#include <hip/hip_bf16.h>

// GRU teacher-forced NLL, B=8192, S=2048, H=8, IN_DIM=4, NCLS=10.
// 8 lanes/element, 1 wave/SIMD. f16 v_dot2_f32_f16 dots (fp32 accumulate,
// init = LDS table entry). All gates in exp2 domain (prescaled log2e / 2log2e).
// Merged z/tanh normalization: hnew = [h0(E+1)+e_z(E-1)]/[(1+e_z)(E+1)],
// one rcp for the whole update (5 gate trans total).
// SOFTWARE PIPELINE: step t's body issues gate dots (h_{t-1}), then the
// LAGGED logits of step t-1 (same H regs), then the lag-2 softmax consume,
// then the gate trans chain -> butterfly. The two lagged blocks are
// independent filler inside the serial exp2/rcp chain.
// Packed-f16 butterfly: pack (h_i,h_{i^1}) then xor2/xor7 DPP on packed regs.
// Dummy prologue contributions cancelled exactly (same-op recompute at init).

#define SEQ   2048
#define BATCH 8192

using hh2 = decltype(__builtin_amdgcn_cvt_pkrtz(0.0f, 0.0f));

template <int CTRL>
static __device__ __forceinline__ int dppi(int x) {
    return __builtin_amdgcn_update_dpp(x, x, CTRL, 0xF, 0xF, true);
}
static __device__ __forceinline__ float xor1f(float x) {
    return __builtin_bit_cast(float, dppi<0xB1>(__builtin_bit_cast(int, x)));
}
static __device__ __forceinline__ float xor2f(float x) {
    return __builtin_bit_cast(float, dppi<0x4E>(__builtin_bit_cast(int, x)));
}
static __device__ __forceinline__ float hmf(float x) {   // lane ^ 7 (ROW_HALF_MIRROR)
    return __builtin_bit_cast(float, dppi<0x141>(__builtin_bit_cast(int, x)));
}
static __device__ __forceinline__ hh2 xor2h(hh2 x) {
    return __builtin_bit_cast(hh2, dppi<0x4E>(__builtin_bit_cast(int, x)));
}
static __device__ __forceinline__ hh2 hmfh(hh2 x) {
    return __builtin_bit_cast(hh2, dppi<0x141>(__builtin_bit_cast(int, x)));
}
static __device__ __forceinline__ float dot2(hh2 a, hh2 b, float c) {
    return __builtin_amdgcn_fdot2(a, b, c, false);
}

__global__ __launch_bounds__(256, 1)
void gru_nll_kernel(const int* __restrict__ xb,
                    const float* __restrict__ Wir, const float* __restrict__ bir,
                    const float* __restrict__ Wiz, const float* __restrict__ biz,
                    const float* __restrict__ Win, const float* __restrict__ bin_,
                    const float* __restrict__ Whr, const float* __restrict__ bhr,
                    const float* __restrict__ Whz, const float* __restrict__ bhz,
                    const float* __restrict__ Whn, const float* __restrict__ bhn,
                    const float* __restrict__ Wout, const float* __restrict__ bout,
                    float* __restrict__ out)
{
    constexpr float S1 = 1.4426950408889634f;   // log2(e)
    __shared__ float4 tbl[10][8];               // [count][i] = {gr', gz', gn', 0}
    __shared__ float  red[256];

    const int tid = threadIdx.x;

    if (tid < 80) {
        int c = tid >> 3, ii = tid & 7;
        float b0 = (float)((c >> 3) & 1);
        float b1 = (float)((c >> 2) & 1);
        float b2 = (float)((c >> 1) & 1);
        float b3 = (float)(c & 1);
        float gr = bir[ii] + bhr[ii]
                 + b0*Wir[ii*4+0] + b1*Wir[ii*4+1] + b2*Wir[ii*4+2] + b3*Wir[ii*4+3];
        float gz = biz[ii] + bhz[ii]
                 + b0*Wiz[ii*4+0] + b1*Wiz[ii*4+1] + b2*Wiz[ii*4+2] + b3*Wiz[ii*4+3];
        float gn = bin_[ii]
                 + b0*Win[ii*4+0] + b1*Win[ii*4+1] + b2*Win[ii*4+2] + b3*Win[ii*4+3];
        tbl[c][ii] = make_float4(S1 * gr, S1 * gz, 2.0f * S1 * gn, 0.0f);
    }
    __syncthreads();

    const int lane = tid & 63;
    const int i    = lane & 7;                    // hidden comp / class owned
    const int b    = blockIdx.x * 32 + (tid >> 3);

    const int perm[8] = {0, 1, 2, 3, 7, 6, 5, 4};

    hh2 whr[4], whz[4], whn[4], wA[4], wB[4];
    #pragma unroll
    for (int q = 0; q < 4; ++q) {
        int c0 = i ^ perm[2*q], c1 = i ^ perm[2*q+1];
        whr[q] = __builtin_amdgcn_cvt_pkrtz(S1 * Whr[i*8 + c0],      S1 * Whr[i*8 + c1]);
        whz[q] = __builtin_amdgcn_cvt_pkrtz(S1 * Whz[i*8 + c0],      S1 * Whz[i*8 + c1]);
        whn[q] = __builtin_amdgcn_cvt_pkrtz(2.0f*S1 * Whn[i*8 + c0], 2.0f*S1 * Whn[i*8 + c1]);
        wA[q]  = __builtin_amdgcn_cvt_pkrtz(S1 * Wout[i*8 + c0],     S1 * Wout[i*8 + c1]);
        wB[q]  = (i < 2)
               ? __builtin_amdgcn_cvt_pkrtz(S1 * Wout[(8+i)*8 + c0], S1 * Wout[(8+i)*8 + c1])
               : __builtin_amdgcn_cvt_pkrtz(0.0f, 0.0f);
    }
    const float ghn_b = 2.0f * S1 * bhn[i];
    const float bA    = S1 * bout[i];
    const float bB    = (i < 2) ? S1 * bout[8+i] : -1e30f;   // exp2 -> 0
    const int clsA    = i;
    const int clsB    = (i < 2) ? 8 + i : 99;                // 99: never matches

    const int4* row4 = (const int4*)(xb + (size_t)b * SEQ);

    hh2 Hh[4];
    #pragma unroll
    for (int q = 0; q < 4; ++q) Hh[q] = __builtin_amdgcn_cvt_pkrtz(0.0f, 0.0f);
    float hprev = 0.0f;                     // own h_i, exact fp32

    float acct = 0.0f;                      // target logits (base-2), x1/elem
    float P    = 1.0f;

    // pending state: sLA/sLB = logits of step cur-2 (consumed this call);
    // tq2 = its target; tq1 = target of step cur-1 (logits computed this call)
    float sLA = 0.0f, sLB = -1e30f;         // dummy: s-sum = 8 exactly
    int   tq1 = -1, tq2 = -1;

    // pre-subtract both dummy contributions EXACTLY:
    //   dummy lag-2 (s=8): log2 = 3;  dummy logits(-1) from h=0: same-op recompute
    float accp;
    {
        float s0 = __builtin_amdgcn_exp2f(bA) + __builtin_amdgcn_exp2f(bB);
        s0 += xor1f(s0);
        s0 += xor2f(s0);
        s0 += hmf(s0);
        accp = -3.0f - __builtin_amdgcn_logf(s0);
    }

    float4 g = tbl[0][i];                   // first input count = 0

    auto consume = [&](float cLA, float cLB, int cT) {
        float s = __builtin_amdgcn_exp2f(cLA) + __builtin_amdgcn_exp2f(cLB);
        s += xor1f(s);
        s += xor2f(s);
        s += hmf(s);        // quad sums quad-uniform: xor7 == xor4
        P *= s;
        float sel = (cT == clsA) ? cLA : ((cT == clsB) ? cLB : 0.0f);
        acct += sel;
    };

    auto stepf = [&](int t) {
        float4 gnx = *(const float4*)&tbl[t][i];   // next input's table entry

        // gate dots on H = h_{cur-1}
        float ar = g.x, az = g.y, hn = ghn_b;
        #pragma unroll
        for (int q = 0; q < 4; ++q) {
            ar = dot2(Hh[q], whr[q], ar);
            az = dot2(Hh[q], whz[q], az);
            hn = dot2(Hh[q], whn[q], hn);
        }
        // lagged logits of step cur-1 (same H regs) — independent filler
        float lA = bA, lB = bB;
        #pragma unroll
        for (int q = 0; q < 4; ++q) {
            lA = dot2(Hh[q], wA[q], lA);
            lB = dot2(Hh[q], wB[q], lB);
        }
        // lag-2 softmax consume — independent filler
        consume(sLA, sLB, tq2);

        // gate trans chain (5 trans), merged z/tanh normalization
        float er = __builtin_amdgcn_exp2f(-ar);
        float ir = __builtin_amdgcn_rcpf(1.0f + er);         // r
        float ez = __builtin_amdgcn_exp2f(-az);
        float u  = __builtin_fmaf(hn, ir, g.z);
        float E  = __builtin_amdgcn_exp2f(u);
        float a_ = E + 1.0f;
        float c_ = E - 1.0f;
        float m_ = ez * c_;
        float num = __builtin_fmaf(hprev, a_, m_);
        float den = a_ * (1.0f + ez);
        float hnew = num * __builtin_amdgcn_rcpf(den);
        hprev = hnew;

        // packed-f16 butterfly: Hh[q] holds cols (i^perm[2q], i^perm[2q+1])
        float v1 = xor1f(hnew);
        hh2 p0 = __builtin_amdgcn_cvt_pkrtz(hnew, v1);
        Hh[0] = p0;
        Hh[1] = xor2h(p0);      // (h_{i^2}, h_{i^3})
        Hh[2] = hmfh(p0);       // (h_{i^7}, h_{i^6})
        Hh[3] = hmfh(Hh[1]);    // (h_{i^5}, h_{i^4})

        // shift pendings
        sLA = lA; sLB = lB;
        tq2 = tq1; tq1 = t;
        g = gnx;
    };

    int4 cc = row4[0];
    int4 cd = row4[1];
    for (int jb = 0; jb < SEQ/8; ++jb) {
        int4 nA = cc, nB = cd;
        if (jb + 1 < SEQ/8) { nA = row4[2*jb + 2]; nB = row4[2*jb + 3]; }
        stepf(cc.x); stepf(cc.y); stepf(cc.z); stepf(cc.w);
        stepf(cd.x); stepf(cd.y); stepf(cd.z); stepf(cd.w);
        accp += __builtin_amdgcn_logf(P);   // log2
        P = 1.0f;
        cc = nA; cd = nB;
    }

    // tail: consume step SEQ-2, then logits+consume for step SEQ-1
    consume(sLA, sLB, tq2);
    {
        float lA = bA, lB = bB;
        #pragma unroll
        for (int q = 0; q < 4; ++q) {
            lA = dot2(Hh[q], wA[q], lA);
            lB = dot2(Hh[q], wB[q], lB);
        }
        consume(lA, lB, tq1);
    }
    accp += __builtin_amdgcn_logf(P);

    red[tid] = __builtin_fmaf(accp, 0.125f, -acct);
    __syncthreads();
    #pragma unroll
    for (int sft = 128; sft > 0; sft >>= 1) {
        if (tid < sft) red[tid] += red[tid + sft];
        __syncthreads();
    }
    if (tid == 0) {
        constexpr float SCALE =
            (float)(0.69314718055994530942 / (8192.0 * 2048.0));
        atomicAdd(out, red[0] * SCALE);
    }
}

extern "C" void kernel_launch(void* const* d_in, const int* in_sizes, int n_in,
                              void* d_out, int out_size, void* d_ws, size_t ws_size,
                              hipStream_t stream) {
    (void)hipMemsetAsync(d_out, 0, sizeof(float), stream);
    gru_nll_kernel<<<BATCH * 8 / 256, 256, 0, stream>>>(
        (const int*)d_in[0],
        (const float*)d_in[1],  (const float*)d_in[2],
        (const float*)d_in[3],  (const float*)d_in[4],
        (const float*)d_in[5],  (const float*)d_in[6],
        (const float*)d_in[7],  (const float*)d_in[8],
        (const float*)d_in[9],  (const float*)d_in[10],
        (const float*)d_in[11], (const float*)d_in[12],
        (const float*)d_in[13], (const float*)d_in[14],
        (float*)d_out);
}